// Round 8
// baseline (474.048 us; speedup 1.0000x reference)
//
#include <hip/hip_runtime.h>
#include <math.h>

// B=64, M=128, J=512, T=513, E=256, H=16, D=16; out (64, 65664) fp32.

#define LDT 68    // 64-row A-tile LDS leading dim (fp32 gemms)
#define LDB 132   // 128-col B-tile LDS leading dim (fp32 gemms)

typedef __attribute__((ext_vector_type(8))) short bf16x8;   // 8 bf16 = 4 VGPR
typedef __attribute__((ext_vector_type(4))) float f32x4;    // MFMA acc

static __device__ inline unsigned short f2bf(float x) {     // RNE fp32->bf16
  unsigned u = __float_as_uint(x);
  return (unsigned short)((u + 0x7fffu + ((u >> 16) & 1u)) >> 16);
}
static __device__ inline float bf2f(unsigned short h) {
  return __uint_as_float(((unsigned)h) << 16);
}
static __device__ inline unsigned pk(unsigned short a, unsigned short b) {
  return (unsigned)a | ((unsigned)b << 16);
}

// ---------------------------------------------------------------------------
// One-time W split+transpose: Wt[col][k] (bf16 hi/lo), col 0..255 = Wk cols,
// 256..511 = Wv cols. grid 512 blocks x 256 thr (thread = k).
// ---------------------------------------------------------------------------
__global__ void prep_wt(const float* __restrict__ Wk, const float* __restrict__ Wv,
                        unsigned short* __restrict__ Wth, unsigned short* __restrict__ Wtl)
{
  const int c = blockIdx.x, k = threadIdx.x;
  const float x = (c < 256) ? Wk[k * 256 + c] : Wv[k * 256 + (c - 256)];
  const unsigned short h = f2bf(x);
  Wth[c * 256 + k] = h;
  Wtl[c * 256 + k] = f2bf(x - bf2f(h));
}

// ---------------------------------------------------------------------------
// Split-bf16 MFMA GEMM: C(32832 x 512) = vjobs(32832 x 256) @ [Wk|Wv].
// 128x128 tile, 256 thr = 4 waves (2x2, each 64x64 via 4x4 16x16x32 tiles).
// C = Ah*Bh + Ah*Bl + Al*Bh  (error ~2^-17, fp32-grade for this use).
// ---------------------------------------------------------------------------
__global__ __launch_bounds__(256) void gemm_kv_mfma(
    const float* __restrict__ jobs, const float* __restrict__ skip,
    const unsigned short* __restrict__ Wth, const unsigned short* __restrict__ Wtl,
    float* __restrict__ Kw, float* __restrict__ Vw)
{
  __shared__ short Ah[128 * 32], Al[128 * 32];   // [row][k] bf16, 8KB each
  __shared__ short Bh[128 * 32], Bl[128 * 32];   // [col][k] bf16
  const int tid = threadIdx.x;
  const int bx = blockIdx.x, by = blockIdx.y;

  const int r16 = tid >> 1;
  const int h16 = (tid & 1) << 4;
  int rg = by * 128 + r16; if (rg > 32831) rg = 32831;
  const int bb = rg / 513, tt = rg - bb * 513;
  const float* arow = (tt == 0) ? skip : (jobs + ((size_t)(bb * 512 + tt - 1) << 8));
  const unsigned short* bhrow = Wth + ((size_t)(bx * 128 + r16) << 8);
  const unsigned short* blrow = Wtl + ((size_t)(bx * 128 + r16) << 8);

  const int w = tid >> 6, lane = tid & 63;
  const int wr = (w >> 1) << 6, wc = (w & 1) << 6;
  const int fm = lane & 15, fq = lane >> 4;

  f32x4 acc[4][4] = {};

  for (int kk = 0; kk < 256; kk += 32) {
    const float4 a0 = *(const float4*)(arow + kk + h16);
    const float4 a1 = *(const float4*)(arow + kk + h16 + 4);
    const float4 a2 = *(const float4*)(arow + kk + h16 + 8);
    const float4 a3 = *(const float4*)(arow + kk + h16 + 12);
    const int4 bh0 = *(const int4*)(bhrow + kk + h16);
    const int4 bh1 = *(const int4*)(bhrow + kk + h16 + 8);
    const int4 bl0 = *(const int4*)(blrow + kk + h16);
    const int4 bl1 = *(const int4*)(blrow + kk + h16 + 8);

    unsigned short h[16], l[16];
    const float av[16] = {a0.x,a0.y,a0.z,a0.w, a1.x,a1.y,a1.z,a1.w,
                          a2.x,a2.y,a2.z,a2.w, a3.x,a3.y,a3.z,a3.w};
    #pragma unroll
    for (int i = 0; i < 16; ++i) {
      h[i] = f2bf(av[i]);
      l[i] = f2bf(av[i] - bf2f(h[i]));
    }

    __syncthreads();
    const int so = r16 * 32 + h16;
    ((int4*)&Ah[so])[0] = make_int4(pk(h[0],h[1]), pk(h[2],h[3]), pk(h[4],h[5]), pk(h[6],h[7]));
    ((int4*)&Ah[so])[1] = make_int4(pk(h[8],h[9]), pk(h[10],h[11]), pk(h[12],h[13]), pk(h[14],h[15]));
    ((int4*)&Al[so])[0] = make_int4(pk(l[0],l[1]), pk(l[2],l[3]), pk(l[4],l[5]), pk(l[6],l[7]));
    ((int4*)&Al[so])[1] = make_int4(pk(l[8],l[9]), pk(l[10],l[11]), pk(l[12],l[13]), pk(l[14],l[15]));
    *(int4*)&Bh[so] = bh0; *(int4*)&Bh[so + 8] = bh1;
    *(int4*)&Bl[so] = bl0; *(int4*)&Bl[so + 8] = bl1;
    __syncthreads();

    bf16x8 afh[4], afl[4], bfh[4], bfl[4];
    #pragma unroll
    for (int i = 0; i < 4; ++i) {
      const int ai = (wr + i * 16 + fm) * 32 + fq * 8;
      const int bi = (wc + i * 16 + fm) * 32 + fq * 8;
      afh[i] = *(const bf16x8*)&Ah[ai];
      afl[i] = *(const bf16x8*)&Al[ai];
      bfh[i] = *(const bf16x8*)&Bh[bi];
      bfl[i] = *(const bf16x8*)&Bl[bi];
    }
    #pragma unroll
    for (int mi = 0; mi < 4; ++mi)
      #pragma unroll
      for (int ni = 0; ni < 4; ++ni) {
        acc[mi][ni] = __builtin_amdgcn_mfma_f32_16x16x32_bf16(afh[mi], bfl[ni], acc[mi][ni], 0, 0, 0);
        acc[mi][ni] = __builtin_amdgcn_mfma_f32_16x16x32_bf16(afl[mi], bfh[ni], acc[mi][ni], 0, 0, 0);
        acc[mi][ni] = __builtin_amdgcn_mfma_f32_16x16x32_bf16(afh[mi], bfh[ni], acc[mi][ni], 0, 0, 0);
      }
  }

  float* Cb = (bx < 2) ? Kw : Vw;
  const int cb = ((bx & 1) << 7) + wc;
  #pragma unroll
  for (int mi = 0; mi < 4; ++mi) {
    #pragma unroll
    for (int r = 0; r < 4; ++r) {
      const int row = by * 128 + wr + mi * 16 + fq * 4 + r;
      if (row < 32832) {
        float* crow = Cb + (size_t)row * 256 + cb;
        #pragma unroll
        for (int ni = 0; ni < 4; ++ni)
          crow[ni * 16 + fm] = acc[mi][ni][r];
      }
    }
  }
}

// ---------------------------------------------------------------------------
// Wide tiled fp32 GEMM (Q and Wc projections): C[rows x 256] = A @ W (+bias)
// ---------------------------------------------------------------------------
template<int MODE>
__global__ __launch_bounds__(256) void gemm_wide(
    const float* __restrict__ A, const float* __restrict__ jobs,
    const float* __restrict__ skip, const float* __restrict__ W1,
    const float* __restrict__ bias, float* __restrict__ C1)
{
  __shared__ float As[16 * LDT];
  __shared__ float Bs[16 * LDB];
  const int tid = threadIdx.x;
  const int bx = blockIdx.x, by = blockIdx.y;

  const float* W = W1; float* C = C1; const int col0 = bx * 128;

  const int a_row = tid >> 2;
  const int a_k4  = (tid & 3) << 2;
  const int row = by * 64 + a_row;
  const float* arow;
  if (MODE == 0) {
    arow = A + ((size_t)row << 8);
  } else {
    const int bb = row / 513;
    const int t  = row - bb * 513;
    arow = (t == 0) ? skip : (jobs + ((size_t)(bb * 512 + t - 1) << 8));
  }

  const int b_k  = tid >> 4;
  const int b_c8 = (tid & 15) << 3;

  const int tr = tid >> 4, tc = tid & 15;
  float acc[4][8] = {};

  for (int k0 = 0; k0 < 256; k0 += 16) {
    const float4 av  = *(const float4*)(arow + k0 + a_k4);
    const float4 bv0 = *(const float4*)(W + ((size_t)(k0 + b_k) << 8) + col0 + b_c8);
    const float4 bv1 = *(const float4*)(W + ((size_t)(k0 + b_k) << 8) + col0 + b_c8 + 4);
    __syncthreads();
    As[(a_k4 + 0) * LDT + a_row] = av.x;
    As[(a_k4 + 1) * LDT + a_row] = av.y;
    As[(a_k4 + 2) * LDT + a_row] = av.z;
    As[(a_k4 + 3) * LDT + a_row] = av.w;
    *(float4*)&Bs[b_k * LDB + b_c8]     = bv0;
    *(float4*)&Bs[b_k * LDB + b_c8 + 4] = bv1;
    __syncthreads();
    #pragma unroll
    for (int k = 0; k < 16; ++k) {
      const float4 a  = *(const float4*)&As[k * LDT + (tr << 2)];
      const float4 b0 = *(const float4*)&Bs[k * LDB + (tc << 3)];
      const float4 b1 = *(const float4*)&Bs[k * LDB + (tc << 3) + 4];
      const float aa[4] = {a.x, a.y, a.z, a.w};
      #pragma unroll
      for (int i = 0; i < 4; ++i) {
        acc[i][0] = fmaf(aa[i], b0.x, acc[i][0]);
        acc[i][1] = fmaf(aa[i], b0.y, acc[i][1]);
        acc[i][2] = fmaf(aa[i], b0.z, acc[i][2]);
        acc[i][3] = fmaf(aa[i], b0.w, acc[i][3]);
        acc[i][4] = fmaf(aa[i], b1.x, acc[i][4]);
        acc[i][5] = fmaf(aa[i], b1.y, acc[i][5]);
        acc[i][6] = fmaf(aa[i], b1.z, acc[i][6]);
        acc[i][7] = fmaf(aa[i], b1.w, acc[i][7]);
      }
    }
  }

  const int oc = col0 + (tc << 3);
  float4 bsa = make_float4(0.f,0.f,0.f,0.f), bsb = make_float4(0.f,0.f,0.f,0.f);
  if (bias) { bsa = *(const float4*)(bias + oc); bsb = *(const float4*)(bias + oc + 4); }
  #pragma unroll
  for (int i = 0; i < 4; ++i) {
    float* crow = C + ((size_t)(by * 64 + (tr << 2) + i) << 8) + oc;
    float4 o0, o1;
    o0.x = acc[i][0]+bsa.x; o0.y = acc[i][1]+bsa.y; o0.z = acc[i][2]+bsa.z; o0.w = acc[i][3]+bsa.w;
    o1.x = acc[i][4]+bsb.x; o1.y = acc[i][5]+bsb.y; o1.z = acc[i][6]+bsb.z; o1.w = acc[i][7]+bsb.w;
    *(float4*)crow = o0; *(float4*)(crow + 4) = o1;
  }
}

// ---------------------------------------------------------------------------
// Attention v5 (fused): one block per (h, b), 512 thr = 8 waves; wave w owns
// T-chunk [w*64, min((w+1)*64, 513)); each lane owns m=lane and m=lane+64.
// Wave id forced scalar via readfirstlane -> K/V pointers provably uniform ->
// s_load scalarization (r7) PLUS 8 waves/SIMD to hide the lgkmcnt waits.
// In-block LDS tree reduction; writes final normalized OC (no combine pass).
// ---------------------------------------------------------------------------
__global__ __launch_bounds__(512, 8) void attn_fused(
    const float* __restrict__ Q, const float* __restrict__ K,
    const float* __restrict__ V, float* __restrict__ OC)
{
  const int h = blockIdx.x, b = blockIdx.y;
  const int tid = threadIdx.x;
  const int lane = tid & 63;
  const int w = __builtin_amdgcn_readfirstlane(tid >> 6);  // 0..7, SGPR
  const int ts = w << 6;
  const int te = (w == 7) ? 513 : (ts + 64);

  __shared__ float red[4 * 128 * 17];    // 34 KB, 4 reduction slots

  float q0[16], q1[16];
  {
    const float* qp0 = Q + ((size_t)(b * 128 + lane) << 8) + h * 16;
    const float* qp1 = qp0 + (64 << 8);
    #pragma unroll
    for (int i = 0; i < 16; i += 4) {
      const float4 a = *(const float4*)(qp0 + i);
      const float4 d = *(const float4*)(qp1 + i);
      q0[i] = a.x * 0.25f; q0[i+1] = a.y * 0.25f; q0[i+2] = a.z * 0.25f; q0[i+3] = a.w * 0.25f;
      q1[i] = d.x * 0.25f; q1[i+1] = d.y * 0.25f; q1[i+2] = d.z * 0.25f; q1[i+3] = d.w * 0.25f;
    }
  }

  float l0 = 0.f, l1 = 0.f, o0[16] = {}, o1[16] = {};
  const float* kp = K + ((size_t)(b * 513 + ts) << 8) + h * 16;
  const float* vp = V + ((size_t)(b * 513 + ts) << 8) + h * 16;

#define DOT16(Q_, P_, S_) do { \
    float s0_ = Q_[0]*(P_)[0];  s0_ = fmaf(Q_[1],(P_)[1],s0_);  s0_ = fmaf(Q_[2],(P_)[2],s0_);  s0_ = fmaf(Q_[3],(P_)[3],s0_); \
    float s1_ = Q_[4]*(P_)[4];  s1_ = fmaf(Q_[5],(P_)[5],s1_);  s1_ = fmaf(Q_[6],(P_)[6],s1_);  s1_ = fmaf(Q_[7],(P_)[7],s1_); \
    float s2_ = Q_[8]*(P_)[8];  s2_ = fmaf(Q_[9],(P_)[9],s2_);  s2_ = fmaf(Q_[10],(P_)[10],s2_); s2_ = fmaf(Q_[11],(P_)[11],s2_); \
    float s3_ = Q_[12]*(P_)[12]; s3_ = fmaf(Q_[13],(P_)[13],s3_); s3_ = fmaf(Q_[14],(P_)[14],s3_); s3_ = fmaf(Q_[15],(P_)[15],s3_); \
    S_ = (s0_ + s1_) + (s2_ + s3_); } while (0)

#define ACC16(O_, E_, P_) do { \
    O_[0]=fmaf(E_,(P_)[0],O_[0]);   O_[1]=fmaf(E_,(P_)[1],O_[1]); \
    O_[2]=fmaf(E_,(P_)[2],O_[2]);   O_[3]=fmaf(E_,(P_)[3],O_[3]); \
    O_[4]=fmaf(E_,(P_)[4],O_[4]);   O_[5]=fmaf(E_,(P_)[5],O_[5]); \
    O_[6]=fmaf(E_,(P_)[6],O_[6]);   O_[7]=fmaf(E_,(P_)[7],O_[7]); \
    O_[8]=fmaf(E_,(P_)[8],O_[8]);   O_[9]=fmaf(E_,(P_)[9],O_[9]); \
    O_[10]=fmaf(E_,(P_)[10],O_[10]); O_[11]=fmaf(E_,(P_)[11],O_[11]); \
    O_[12]=fmaf(E_,(P_)[12],O_[12]); O_[13]=fmaf(E_,(P_)[13],O_[13]); \
    O_[14]=fmaf(E_,(P_)[14],O_[14]); O_[15]=fmaf(E_,(P_)[15],O_[15]); } while (0)

  int t = ts;
  for (; t + 1 < te; t += 2) {
    float ea0, eb0, ea1, eb1;
    {
      const float* ka = kp;          // rows t, t+1 (uniform -> SGPRs)
      const float* kb = kp + 256;
      DOT16(q0, ka, ea0); DOT16(q0, kb, eb0);
      DOT16(q1, ka, ea1); DOT16(q1, kb, eb1);
    }
    ea0 = __expf(ea0); eb0 = __expf(eb0);
    ea1 = __expf(ea1); eb1 = __expf(eb1);
    l0 += ea0 + eb0; l1 += ea1 + eb1;
    {
      const float* va = vp;
      const float* vb = vp + 256;
      ACC16(o0, ea0, va); ACC16(o0, eb0, vb);
      ACC16(o1, ea1, va); ACC16(o1, eb1, vb);
    }
    kp += 512; vp += 512;
  }
  if (t < te) {   // odd tail (wave 7 only: 65 rows)
    float s0, s1;
    DOT16(q0, kp, s0); DOT16(q1, kp, s1);
    const float e0 = __expf(s0), e1 = __expf(s1);
    l0 += e0; l1 += e1;
    ACC16(o0, e0, vp); ACC16(o1, e1, vp);
  }
#undef DOT16
#undef ACC16

  // ---- 3-stage LDS tree reduction across the 8 waves ----
  const int base0 = lane * 17, base1 = (lane + 64) * 17;
  if (w >= 4) {                       // waves 4..7 -> slots 0..3
    float* s = red + (w - 4) * 2176;
    #pragma unroll
    for (int i = 0; i < 16; ++i) { s[base0 + i] = o0[i]; s[base1 + i] = o1[i]; }
    s[base0 + 16] = l0; s[base1 + 16] = l1;
  }
  __syncthreads();
  if (w < 4) {
    const float* s = red + w * 2176;
    #pragma unroll
    for (int i = 0; i < 16; ++i) { o0[i] += s[base0 + i]; o1[i] += s[base1 + i]; }
    l0 += s[base0 + 16]; l1 += s[base1 + 16];
  }
  __syncthreads();
  if (w == 2 || w == 3) {             // waves 2,3 -> slots 0,1
    float* s = red + (w - 2) * 2176;
    #pragma unroll
    for (int i = 0; i < 16; ++i) { s[base0 + i] = o0[i]; s[base1 + i] = o1[i]; }
    s[base0 + 16] = l0; s[base1 + 16] = l1;
  }
  __syncthreads();
  if (w < 2) {
    const float* s = red + w * 2176;
    #pragma unroll
    for (int i = 0; i < 16; ++i) { o0[i] += s[base0 + i]; o1[i] += s[base1 + i]; }
    l0 += s[base0 + 16]; l1 += s[base1 + 16];
  }
  __syncthreads();
  if (w == 1) {                       // wave 1 -> slot 0
    float* s = red;
    #pragma unroll
    for (int i = 0; i < 16; ++i) { s[base0 + i] = o0[i]; s[base1 + i] = o1[i]; }
    s[base0 + 16] = l0; s[base1 + 16] = l1;
  }
  __syncthreads();
  if (w == 0) {
    const float* s = red;
    #pragma unroll
    for (int i = 0; i < 16; ++i) { o0[i] += s[base0 + i]; o1[i] += s[base1 + i]; }
    l0 += s[base0 + 16]; l1 += s[base1 + 16];
    const float inv0 = 1.f / l0, inv1 = 1.f / l1;
    float* op0 = OC + ((size_t)(b * 128 + lane) << 8) + h * 16;
    float* op1 = op0 + (64 << 8);
    #pragma unroll
    for (int i = 0; i < 16; i += 4) {
      float4 v0; v0.x = o0[i]*inv0; v0.y = o0[i+1]*inv0; v0.z = o0[i+2]*inv0; v0.w = o0[i+3]*inv0;
      float4 v1; v1.x = o1[i]*inv1; v1.y = o1[i+1]*inv1; v1.z = o1[i+2]*inv1; v1.w = o1[i+3]*inv1;
      *(float4*)(op0 + i) = v0;
      *(float4*)(op1 + i) = v1;
    }
  }
}

// ---------------------------------------------------------------------------
// Logits GEMM, fused exp(10*tanh(x/16)+mask-10) + deterministic partials.
// ---------------------------------------------------------------------------
__global__ __launch_bounds__(256) void logits_gemm(
    const float* __restrict__ MH, const float* __restrict__ jobs,
    const float* __restrict__ skip, const float* __restrict__ mask,
    float* __restrict__ out, float* __restrict__ partials)
{
  __shared__ float As[16 * LDT];
  __shared__ float Bs[16 * LDT];
  __shared__ float red[4];
  const int tid = threadIdx.x;
  const int b = blockIdx.z;

  const int m_l = tid >> 2;
  const int kk4 = (tid & 3) << 2;
  const float* arow = MH + ((size_t)(b * 128 + blockIdx.y * 64 + m_l) << 8);

  const int t_g = blockIdx.x * 64 + m_l;
  const float* brow = nullptr;
  if (t_g < 513)
    brow = (t_g == 0) ? skip : (jobs + ((size_t)(b * 512 + t_g - 1) << 8));

  const int tr = tid >> 4, tc = tid & 15;
  float acc[4][4] = {};

  for (int k0 = 0; k0 < 256; k0 += 16) {
    const float4 av = *(const float4*)(arow + k0 + kk4);
    float4 bv = make_float4(0.f, 0.f, 0.f, 0.f);
    if (brow) bv = *(const float4*)(brow + k0 + kk4);
    __syncthreads();
    As[(kk4 + 0) * LDT + m_l] = av.x;
    As[(kk4 + 1) * LDT + m_l] = av.y;
    As[(kk4 + 2) * LDT + m_l] = av.z;
    As[(kk4 + 3) * LDT + m_l] = av.w;
    Bs[(kk4 + 0) * LDT + m_l] = bv.x;
    Bs[(kk4 + 1) * LDT + m_l] = bv.y;
    Bs[(kk4 + 2) * LDT + m_l] = bv.z;
    Bs[(kk4 + 3) * LDT + m_l] = bv.w;
    __syncthreads();
    #pragma unroll
    for (int k = 0; k < 16; ++k) {
      const float4 a  = *(const float4*)&As[k * LDT + (tr << 2)];
      const float4 b4 = *(const float4*)&Bs[k * LDT + (tc << 2)];
      const float aa[4] = {a.x, a.y, a.z, a.w};
      #pragma unroll
      for (int i = 0; i < 4; ++i) {
        acc[i][0] = fmaf(aa[i], b4.x, acc[i][0]);
        acc[i][1] = fmaf(aa[i], b4.y, acc[i][1]);
        acc[i][2] = fmaf(aa[i], b4.z, acc[i][2]);
        acc[i][3] = fmaf(aa[i], b4.w, acc[i][3]);
      }
    }
  }

  float lsum = 0.f;
  #pragma unroll
  for (int i = 0; i < 4; ++i) {
    const int mm = blockIdx.y * 64 + (tr << 2) + i;
    #pragma unroll
    for (int j = 0; j < 4; ++j) {
      const int tt = blockIdx.x * 64 + (tc << 2) + j;
      if (tt < 513) {
        const float lg = 10.f * tanhf(acc[i][j] * 0.0625f)
                       + mask[((size_t)(b * 128 + mm)) * 513 + tt];
        const float e = __expf(lg - 10.f);
        out[(size_t)b * 65664 + (size_t)mm * 513 + tt] = e;
        lsum += e;
      }
    }
  }
  #pragma unroll
  for (int off = 32; off; off >>= 1) lsum += __shfl_xor(lsum, off);
  if ((tid & 63) == 0) red[tid >> 6] = lsum;
  __syncthreads();
  if (tid == 0)
    partials[b * 18 + blockIdx.x * 2 + blockIdx.y] =
        (red[0] + red[1]) + (red[2] + red[3]);
}

__global__ void sm_inv(const float* __restrict__ partials, float* __restrict__ invb)
{
  const int b = threadIdx.x;
  if (b < 64) {
    float s = 0.f;
    #pragma unroll
    for (int i = 0; i < 18; ++i) s += partials[b * 18 + i];
    invb[b] = 1.f / s;
  }
}

__global__ __launch_bounds__(256) void sm_norm(float* __restrict__ out,
                                               const float* __restrict__ invb)
{
  const int i4 = blockIdx.x * 256 + threadIdx.x;
  if (i4 < 1050624) {
    const int b = i4 / 16416;
    float4 v = ((float4*)out)[i4];
    const float s = invb[b];
    v.x *= s; v.y *= s; v.z *= s; v.w *= s;
    ((float4*)out)[i4] = v;
  }
}

// ---------------------------------------------------------------------------
extern "C" void kernel_launch(void* const* d_in, const int* in_sizes, int n_in,
                              void* d_out, int out_size, void* d_ws, size_t ws_size,
                              hipStream_t stream)
{
  const float* machine = (const float*)d_in[0];
  const float* jobs    = (const float*)d_in[1];
  const float* mask    = (const float*)d_in[2];
  const float* Wq      = (const float*)d_in[3];
  const float* Wk      = (const float*)d_in[4];
  const float* Wv      = (const float*)d_in[5];
  const float* Wc      = (const float*)d_in[6];
  const float* bc      = (const float*)d_in[7];
  const float* skip    = (const float*)d_in[8];

  // Workspace (floats). Peak 20,905,088 f ~ 83.6 MB.
  //   [0,        2097152)  Qw; overwritten in-place by attn_fused as OC
  //   [2097152, 10502144)  Kw; first 1216 f reused as partials/invb after attn
  //   [10502144,18907136)  Vw
  //   [18907136,...)       Wth/Wtl (bf16) -> dead after kv gemm -> MH
  float* ws       = (float*)d_ws;
  float* Qw       = ws;
  float* Kw       = ws + 2097152;
  float* Vw       = ws + 10502144;
  unsigned short* Wth = (unsigned short*)(ws + 18907136);
  unsigned short* Wtl = Wth + 131072;
  float* MH       = ws + 18907136;     // overlays Wt (dead by then)
  float* partials = ws + 2097152;      // overlays Kw (dead after attn)
  float* invb     = partials + 1152;
  float* OC       = Qw;                // attn writes its own (h,b) slice only
  float* out      = (float*)d_out;

  // Q = machine @ Wq3 (fp32)
  gemm_wide<0><<<dim3(2, 128), 256, 0, stream>>>(
      machine, nullptr, nullptr, Wq, nullptr, Qw);
  // W split/transpose, then K|V = vjobs @ [Wk|Wv] via split-bf16 MFMA
  prep_wt<<<512, 256, 0, stream>>>(Wk, Wv, Wth, Wtl);
  gemm_kv_mfma<<<dim3(4, 257), 256, 0, stream>>>(jobs, skip, Wth, Wtl, Kw, Vw);
  // fused attention: 8 T-chunk waves per (h,b), in-block reduce, writes OC
  attn_fused<<<dim3(16, 64), 512, 0, stream>>>(Qw, Kw, Vw, OC);
  // mh = out_concat @ Wc + bc (fp32)
  gemm_wide<0><<<dim3(2, 128), 256, 0, stream>>>(
      OC, nullptr, nullptr, Wc, bc, MH);
  // exp(logits-10) + partials
  logits_gemm<<<dim3(9, 2, 64), 256, 0, stream>>>(MH, jobs, skip, mask, out, partials);
  sm_inv<<<1, 64, 0, stream>>>(partials, invb);
  sm_norm<<<4104, 256, 0, stream>>>(out, invb);
}

// Round 9
// 337.766 us; speedup vs baseline: 1.4035x; 1.4035x over previous
//
#include <hip/hip_runtime.h>
#include <math.h>

// B=64, M=128, J=512, T=513, E=256, H=16, D=16; out (64, 65664) fp32.

#define LDT 68    // 64-row A-tile LDS leading dim (fp32 gemms)
#define LDB 132   // 128-col B-tile LDS leading dim (fp32 gemms)

typedef __attribute__((ext_vector_type(8))) short bf16x8;   // 8 bf16 = 4 VGPR
typedef __attribute__((ext_vector_type(4))) float f32x4;    // MFMA acc

static __device__ inline unsigned short f2bf(float x) {     // RNE fp32->bf16
  unsigned u = __float_as_uint(x);
  return (unsigned short)((u + 0x7fffu + ((u >> 16) & 1u)) >> 16);
}
static __device__ inline float bf2f(unsigned short h) {
  return __uint_as_float(((unsigned)h) << 16);
}
static __device__ inline unsigned pk(unsigned short a, unsigned short b) {
  return (unsigned)a | ((unsigned)b << 16);
}

// ---------------------------------------------------------------------------
// One-time W split+transpose: Wt[col][k] (bf16 hi/lo), col 0..255 = Wk cols,
// 256..511 = Wv cols. grid 512 blocks x 256 thr (thread = k).
// ---------------------------------------------------------------------------
__global__ void prep_wt(const float* __restrict__ Wk, const float* __restrict__ Wv,
                        unsigned short* __restrict__ Wth, unsigned short* __restrict__ Wtl)
{
  const int c = blockIdx.x, k = threadIdx.x;
  const float x = (c < 256) ? Wk[k * 256 + c] : Wv[k * 256 + (c - 256)];
  const unsigned short h = f2bf(x);
  Wth[c * 256 + k] = h;
  Wtl[c * 256 + k] = f2bf(x - bf2f(h));
}

// ---------------------------------------------------------------------------
// Split-bf16 MFMA GEMM: C(32832 x 512) = vjobs(32832 x 256) @ [Wk|Wv].
// 128x128 tile, 256 thr = 4 waves (2x2, each 64x64 via 4x4 16x16x32 tiles).
// C = Ah*Bh + Ah*Bl + Al*Bh  (error ~2^-17, fp32-grade for this use).
// ---------------------------------------------------------------------------
__global__ __launch_bounds__(256) void gemm_kv_mfma(
    const float* __restrict__ jobs, const float* __restrict__ skip,
    const unsigned short* __restrict__ Wth, const unsigned short* __restrict__ Wtl,
    float* __restrict__ Kw, float* __restrict__ Vw)
{
  __shared__ short Ah[128 * 32], Al[128 * 32];   // [row][k] bf16, 8KB each
  __shared__ short Bh[128 * 32], Bl[128 * 32];   // [col][k] bf16
  const int tid = threadIdx.x;
  const int bx = blockIdx.x, by = blockIdx.y;

  const int r16 = tid >> 1;
  const int h16 = (tid & 1) << 4;
  int rg = by * 128 + r16; if (rg > 32831) rg = 32831;
  const int bb = rg / 513, tt = rg - bb * 513;
  const float* arow = (tt == 0) ? skip : (jobs + ((size_t)(bb * 512 + tt - 1) << 8));
  const unsigned short* bhrow = Wth + ((size_t)(bx * 128 + r16) << 8);
  const unsigned short* blrow = Wtl + ((size_t)(bx * 128 + r16) << 8);

  const int w = tid >> 6, lane = tid & 63;
  const int wr = (w >> 1) << 6, wc = (w & 1) << 6;
  const int fm = lane & 15, fq = lane >> 4;

  f32x4 acc[4][4] = {};

  for (int kk = 0; kk < 256; kk += 32) {
    const float4 a0 = *(const float4*)(arow + kk + h16);
    const float4 a1 = *(const float4*)(arow + kk + h16 + 4);
    const float4 a2 = *(const float4*)(arow + kk + h16 + 8);
    const float4 a3 = *(const float4*)(arow + kk + h16 + 12);
    const int4 bh0 = *(const int4*)(bhrow + kk + h16);
    const int4 bh1 = *(const int4*)(bhrow + kk + h16 + 8);
    const int4 bl0 = *(const int4*)(blrow + kk + h16);
    const int4 bl1 = *(const int4*)(blrow + kk + h16 + 8);

    unsigned short h[16], l[16];
    const float av[16] = {a0.x,a0.y,a0.z,a0.w, a1.x,a1.y,a1.z,a1.w,
                          a2.x,a2.y,a2.z,a2.w, a3.x,a3.y,a3.z,a3.w};
    #pragma unroll
    for (int i = 0; i < 16; ++i) {
      h[i] = f2bf(av[i]);
      l[i] = f2bf(av[i] - bf2f(h[i]));
    }

    __syncthreads();
    const int so = r16 * 32 + h16;
    ((int4*)&Ah[so])[0] = make_int4(pk(h[0],h[1]), pk(h[2],h[3]), pk(h[4],h[5]), pk(h[6],h[7]));
    ((int4*)&Ah[so])[1] = make_int4(pk(h[8],h[9]), pk(h[10],h[11]), pk(h[12],h[13]), pk(h[14],h[15]));
    ((int4*)&Al[so])[0] = make_int4(pk(l[0],l[1]), pk(l[2],l[3]), pk(l[4],l[5]), pk(l[6],l[7]));
    ((int4*)&Al[so])[1] = make_int4(pk(l[8],l[9]), pk(l[10],l[11]), pk(l[12],l[13]), pk(l[14],l[15]));
    *(int4*)&Bh[so] = bh0; *(int4*)&Bh[so + 8] = bh1;
    *(int4*)&Bl[so] = bl0; *(int4*)&Bl[so + 8] = bl1;
    __syncthreads();

    bf16x8 afh[4], afl[4], bfh[4], bfl[4];
    #pragma unroll
    for (int i = 0; i < 4; ++i) {
      const int ai = (wr + i * 16 + fm) * 32 + fq * 8;
      const int bi = (wc + i * 16 + fm) * 32 + fq * 8;
      afh[i] = *(const bf16x8*)&Ah[ai];
      afl[i] = *(const bf16x8*)&Al[ai];
      bfh[i] = *(const bf16x8*)&Bh[bi];
      bfl[i] = *(const bf16x8*)&Bl[bi];
    }
    #pragma unroll
    for (int mi = 0; mi < 4; ++mi)
      #pragma unroll
      for (int ni = 0; ni < 4; ++ni) {
        acc[mi][ni] = __builtin_amdgcn_mfma_f32_16x16x32_bf16(afh[mi], bfl[ni], acc[mi][ni], 0, 0, 0);
        acc[mi][ni] = __builtin_amdgcn_mfma_f32_16x16x32_bf16(afl[mi], bfh[ni], acc[mi][ni], 0, 0, 0);
        acc[mi][ni] = __builtin_amdgcn_mfma_f32_16x16x32_bf16(afh[mi], bfh[ni], acc[mi][ni], 0, 0, 0);
      }
  }

  float* Cb = (bx < 2) ? Kw : Vw;
  const int cb = ((bx & 1) << 7) + wc;
  #pragma unroll
  for (int mi = 0; mi < 4; ++mi) {
    #pragma unroll
    for (int r = 0; r < 4; ++r) {
      const int row = by * 128 + wr + mi * 16 + fq * 4 + r;
      if (row < 32832) {
        float* crow = Cb + (size_t)row * 256 + cb;
        #pragma unroll
        for (int ni = 0; ni < 4; ++ni)
          crow[ni * 16 + fm] = acc[mi][ni][r];
      }
    }
  }
}

// ---------------------------------------------------------------------------
// Wide tiled fp32 GEMM (Q and Wc projections): C[rows x 256] = A @ W (+bias)
// ---------------------------------------------------------------------------
template<int MODE>
__global__ __launch_bounds__(256) void gemm_wide(
    const float* __restrict__ A, const float* __restrict__ jobs,
    const float* __restrict__ skip, const float* __restrict__ W1,
    const float* __restrict__ bias, float* __restrict__ C1)
{
  __shared__ float As[16 * LDT];
  __shared__ float Bs[16 * LDB];
  const int tid = threadIdx.x;
  const int bx = blockIdx.x, by = blockIdx.y;

  const float* W = W1; float* C = C1; const int col0 = bx * 128;

  const int a_row = tid >> 2;
  const int a_k4  = (tid & 3) << 2;
  const int row = by * 64 + a_row;
  const float* arow;
  if (MODE == 0) {
    arow = A + ((size_t)row << 8);
  } else {
    const int bb = row / 513;
    const int t  = row - bb * 513;
    arow = (t == 0) ? skip : (jobs + ((size_t)(bb * 512 + t - 1) << 8));
  }

  const int b_k  = tid >> 4;
  const int b_c8 = (tid & 15) << 3;

  const int tr = tid >> 4, tc = tid & 15;
  float acc[4][8] = {};

  for (int k0 = 0; k0 < 256; k0 += 16) {
    const float4 av  = *(const float4*)(arow + k0 + a_k4);
    const float4 bv0 = *(const float4*)(W + ((size_t)(k0 + b_k) << 8) + col0 + b_c8);
    const float4 bv1 = *(const float4*)(W + ((size_t)(k0 + b_k) << 8) + col0 + b_c8 + 4);
    __syncthreads();
    As[(a_k4 + 0) * LDT + a_row] = av.x;
    As[(a_k4 + 1) * LDT + a_row] = av.y;
    As[(a_k4 + 2) * LDT + a_row] = av.z;
    As[(a_k4 + 3) * LDT + a_row] = av.w;
    *(float4*)&Bs[b_k * LDB + b_c8]     = bv0;
    *(float4*)&Bs[b_k * LDB + b_c8 + 4] = bv1;
    __syncthreads();
    #pragma unroll
    for (int k = 0; k < 16; ++k) {
      const float4 a  = *(const float4*)&As[k * LDT + (tr << 2)];
      const float4 b0 = *(const float4*)&Bs[k * LDB + (tc << 3)];
      const float4 b1 = *(const float4*)&Bs[k * LDB + (tc << 3) + 4];
      const float aa[4] = {a.x, a.y, a.z, a.w};
      #pragma unroll
      for (int i = 0; i < 4; ++i) {
        acc[i][0] = fmaf(aa[i], b0.x, acc[i][0]);
        acc[i][1] = fmaf(aa[i], b0.y, acc[i][1]);
        acc[i][2] = fmaf(aa[i], b0.z, acc[i][2]);
        acc[i][3] = fmaf(aa[i], b0.w, acc[i][3]);
        acc[i][4] = fmaf(aa[i], b1.x, acc[i][4]);
        acc[i][5] = fmaf(aa[i], b1.y, acc[i][5]);
        acc[i][6] = fmaf(aa[i], b1.z, acc[i][6]);
        acc[i][7] = fmaf(aa[i], b1.w, acc[i][7]);
      }
    }
  }

  const int oc = col0 + (tc << 3);
  float4 bsa = make_float4(0.f,0.f,0.f,0.f), bsb = make_float4(0.f,0.f,0.f,0.f);
  if (bias) { bsa = *(const float4*)(bias + oc); bsb = *(const float4*)(bias + oc + 4); }
  #pragma unroll
  for (int i = 0; i < 4; ++i) {
    float* crow = C + ((size_t)(by * 64 + (tr << 2) + i) << 8) + oc;
    float4 o0, o1;
    o0.x = acc[i][0]+bsa.x; o0.y = acc[i][1]+bsa.y; o0.z = acc[i][2]+bsa.z; o0.w = acc[i][3]+bsa.w;
    o1.x = acc[i][4]+bsb.x; o1.y = acc[i][5]+bsb.y; o1.z = acc[i][6]+bsb.z; o1.w = acc[i][7]+bsb.w;
    *(float4*)crow = o0; *(float4*)(crow + 4) = o1;
  }
}

// ---------------------------------------------------------------------------
// Attention v6 (fused): one block per (h, b), 256 thr = 4 waves; wave w owns
// T-chunk [w*128, min(w*128+128, 513)); each lane owns m=lane and m=lane+64.
// launch_bounds(256,4) -> 128-VGPR cap fits the ~100-VGPR working set (r8's
// (512,8) forced a 64-VGPR cap -> inner-loop accumulator spill, +128 MB
// scratch traffic). readfirstlane keeps K/V s_loads scalar; 4 waves/SIMD
// (2x r7) hide the lgkmcnt waits. 2-stage LDS tree reduce, writes final OC.
// ---------------------------------------------------------------------------
__global__ __launch_bounds__(256, 4) void attn_fused(
    const float* __restrict__ Q, const float* __restrict__ K,
    const float* __restrict__ V, float* __restrict__ OC)
{
  const int h = blockIdx.x, b = blockIdx.y;
  const int tid = threadIdx.x;
  const int lane = tid & 63;
  const int w = __builtin_amdgcn_readfirstlane(tid >> 6);  // 0..3, SGPR
  const int ts = w << 7;
  const int te = (w == 3) ? 513 : (ts + 128);

  __shared__ float red[2 * 128 * 17];    // 17 KB, 2 reduction slots

  float q0[16], q1[16];
  {
    const float* qp0 = Q + ((size_t)(b * 128 + lane) << 8) + h * 16;
    const float* qp1 = qp0 + (64 << 8);
    #pragma unroll
    for (int i = 0; i < 16; i += 4) {
      const float4 a = *(const float4*)(qp0 + i);
      const float4 d = *(const float4*)(qp1 + i);
      q0[i] = a.x * 0.25f; q0[i+1] = a.y * 0.25f; q0[i+2] = a.z * 0.25f; q0[i+3] = a.w * 0.25f;
      q1[i] = d.x * 0.25f; q1[i+1] = d.y * 0.25f; q1[i+2] = d.z * 0.25f; q1[i+3] = d.w * 0.25f;
    }
  }

  float l0 = 0.f, l1 = 0.f, o0[16] = {}, o1[16] = {};
  const float* kp = K + ((size_t)(b * 513 + ts) << 8) + h * 16;
  const float* vp = V + ((size_t)(b * 513 + ts) << 8) + h * 16;

#define DOT16(Q_, P_, S_) do { \
    float s0_ = Q_[0]*(P_)[0];  s0_ = fmaf(Q_[1],(P_)[1],s0_);  s0_ = fmaf(Q_[2],(P_)[2],s0_);  s0_ = fmaf(Q_[3],(P_)[3],s0_); \
    float s1_ = Q_[4]*(P_)[4];  s1_ = fmaf(Q_[5],(P_)[5],s1_);  s1_ = fmaf(Q_[6],(P_)[6],s1_);  s1_ = fmaf(Q_[7],(P_)[7],s1_); \
    float s2_ = Q_[8]*(P_)[8];  s2_ = fmaf(Q_[9],(P_)[9],s2_);  s2_ = fmaf(Q_[10],(P_)[10],s2_); s2_ = fmaf(Q_[11],(P_)[11],s2_); \
    float s3_ = Q_[12]*(P_)[12]; s3_ = fmaf(Q_[13],(P_)[13],s3_); s3_ = fmaf(Q_[14],(P_)[14],s3_); s3_ = fmaf(Q_[15],(P_)[15],s3_); \
    S_ = (s0_ + s1_) + (s2_ + s3_); } while (0)

#define ACC16(O_, E_, P_) do { \
    O_[0]=fmaf(E_,(P_)[0],O_[0]);   O_[1]=fmaf(E_,(P_)[1],O_[1]); \
    O_[2]=fmaf(E_,(P_)[2],O_[2]);   O_[3]=fmaf(E_,(P_)[3],O_[3]); \
    O_[4]=fmaf(E_,(P_)[4],O_[4]);   O_[5]=fmaf(E_,(P_)[5],O_[5]); \
    O_[6]=fmaf(E_,(P_)[6],O_[6]);   O_[7]=fmaf(E_,(P_)[7],O_[7]); \
    O_[8]=fmaf(E_,(P_)[8],O_[8]);   O_[9]=fmaf(E_,(P_)[9],O_[9]); \
    O_[10]=fmaf(E_,(P_)[10],O_[10]); O_[11]=fmaf(E_,(P_)[11],O_[11]); \
    O_[12]=fmaf(E_,(P_)[12],O_[12]); O_[13]=fmaf(E_,(P_)[13],O_[13]); \
    O_[14]=fmaf(E_,(P_)[14],O_[14]); O_[15]=fmaf(E_,(P_)[15],O_[15]); } while (0)

  int t = ts;
  for (; t + 1 < te; t += 2) {
    float ea0, eb0, ea1, eb1;
    {
      const float* ka = kp;          // rows t, t+1 (uniform -> SGPRs)
      const float* kb = kp + 256;
      DOT16(q0, ka, ea0); DOT16(q0, kb, eb0);
      DOT16(q1, ka, ea1); DOT16(q1, kb, eb1);
    }
    ea0 = __expf(ea0); eb0 = __expf(eb0);
    ea1 = __expf(ea1); eb1 = __expf(eb1);
    l0 += ea0 + eb0; l1 += ea1 + eb1;
    {
      const float* va = vp;
      const float* vb = vp + 256;
      ACC16(o0, ea0, va); ACC16(o0, eb0, vb);
      ACC16(o1, ea1, va); ACC16(o1, eb1, vb);
    }
    kp += 512; vp += 512;
  }
  if (t < te) {   // odd tail (wave 3 only: 129 rows)
    float s0, s1;
    DOT16(q0, kp, s0); DOT16(q1, kp, s1);
    const float e0 = __expf(s0), e1 = __expf(s1);
    l0 += e0; l1 += e1;
    ACC16(o0, e0, vp); ACC16(o1, e1, vp);
  }
#undef DOT16
#undef ACC16

  // ---- 2-stage LDS tree reduction across the 4 waves ----
  const int base0 = lane * 17, base1 = (lane + 64) * 17;
  if (w >= 2) {                       // waves 2,3 -> slots 0,1
    float* s = red + (w - 2) * 2176;
    #pragma unroll
    for (int i = 0; i < 16; ++i) { s[base0 + i] = o0[i]; s[base1 + i] = o1[i]; }
    s[base0 + 16] = l0; s[base1 + 16] = l1;
  }
  __syncthreads();
  if (w < 2) {
    const float* s = red + w * 2176;
    #pragma unroll
    for (int i = 0; i < 16; ++i) { o0[i] += s[base0 + i]; o1[i] += s[base1 + i]; }
    l0 += s[base0 + 16]; l1 += s[base1 + 16];
  }
  __syncthreads();
  if (w == 1) {                       // wave 1 -> slot 0
    float* s = red;
    #pragma unroll
    for (int i = 0; i < 16; ++i) { s[base0 + i] = o0[i]; s[base1 + i] = o1[i]; }
    s[base0 + 16] = l0; s[base1 + 16] = l1;
  }
  __syncthreads();
  if (w == 0) {
    const float* s = red;
    #pragma unroll
    for (int i = 0; i < 16; ++i) { o0[i] += s[base0 + i]; o1[i] += s[base1 + i]; }
    l0 += s[base0 + 16]; l1 += s[base1 + 16];
    const float inv0 = 1.f / l0, inv1 = 1.f / l1;
    float* op0 = OC + ((size_t)(b * 128 + lane) << 8) + h * 16;
    float* op1 = op0 + (64 << 8);
    #pragma unroll
    for (int i = 0; i < 16; i += 4) {
      float4 v0; v0.x = o0[i]*inv0; v0.y = o0[i+1]*inv0; v0.z = o0[i+2]*inv0; v0.w = o0[i+3]*inv0;
      float4 v1; v1.x = o1[i]*inv1; v1.y = o1[i+1]*inv1; v1.z = o1[i+2]*inv1; v1.w = o1[i+3]*inv1;
      *(float4*)(op0 + i) = v0;
      *(float4*)(op1 + i) = v1;
    }
  }
}

// ---------------------------------------------------------------------------
// Logits GEMM, fused exp(10*tanh(x/16)+mask-10) + deterministic partials.
// ---------------------------------------------------------------------------
__global__ __launch_bounds__(256) void logits_gemm(
    const float* __restrict__ MH, const float* __restrict__ jobs,
    const float* __restrict__ skip, const float* __restrict__ mask,
    float* __restrict__ out, float* __restrict__ partials)
{
  __shared__ float As[16 * LDT];
  __shared__ float Bs[16 * LDT];
  __shared__ float red[4];
  const int tid = threadIdx.x;
  const int b = blockIdx.z;

  const int m_l = tid >> 2;
  const int kk4 = (tid & 3) << 2;
  const float* arow = MH + ((size_t)(b * 128 + blockIdx.y * 64 + m_l) << 8);

  const int t_g = blockIdx.x * 64 + m_l;
  const float* brow = nullptr;
  if (t_g < 513)
    brow = (t_g == 0) ? skip : (jobs + ((size_t)(b * 512 + t_g - 1) << 8));

  const int tr = tid >> 4, tc = tid & 15;
  float acc[4][4] = {};

  for (int k0 = 0; k0 < 256; k0 += 16) {
    const float4 av = *(const float4*)(arow + k0 + kk4);
    float4 bv = make_float4(0.f, 0.f, 0.f, 0.f);
    if (brow) bv = *(const float4*)(brow + k0 + kk4);
    __syncthreads();
    As[(kk4 + 0) * LDT + m_l] = av.x;
    As[(kk4 + 1) * LDT + m_l] = av.y;
    As[(kk4 + 2) * LDT + m_l] = av.z;
    As[(kk4 + 3) * LDT + m_l] = av.w;
    Bs[(kk4 + 0) * LDT + m_l] = bv.x;
    Bs[(kk4 + 1) * LDT + m_l] = bv.y;
    Bs[(kk4 + 2) * LDT + m_l] = bv.z;
    Bs[(kk4 + 3) * LDT + m_l] = bv.w;
    __syncthreads();
    #pragma unroll
    for (int k = 0; k < 16; ++k) {
      const float4 a  = *(const float4*)&As[k * LDT + (tr << 2)];
      const float4 b4 = *(const float4*)&Bs[k * LDT + (tc << 2)];
      const float aa[4] = {a.x, a.y, a.z, a.w};
      #pragma unroll
      for (int i = 0; i < 4; ++i) {
        acc[i][0] = fmaf(aa[i], b4.x, acc[i][0]);
        acc[i][1] = fmaf(aa[i], b4.y, acc[i][1]);
        acc[i][2] = fmaf(aa[i], b4.z, acc[i][2]);
        acc[i][3] = fmaf(aa[i], b4.w, acc[i][3]);
      }
    }
  }

  float lsum = 0.f;
  #pragma unroll
  for (int i = 0; i < 4; ++i) {
    const int mm = blockIdx.y * 64 + (tr << 2) + i;
    #pragma unroll
    for (int j = 0; j < 4; ++j) {
      const int tt = blockIdx.x * 64 + (tc << 2) + j;
      if (tt < 513) {
        const float lg = 10.f * tanhf(acc[i][j] * 0.0625f)
                       + mask[((size_t)(b * 128 + mm)) * 513 + tt];
        const float e = __expf(lg - 10.f);
        out[(size_t)b * 65664 + (size_t)mm * 513 + tt] = e;
        lsum += e;
      }
    }
  }
  #pragma unroll
  for (int off = 32; off; off >>= 1) lsum += __shfl_xor(lsum, off);
  if ((tid & 63) == 0) red[tid >> 6] = lsum;
  __syncthreads();
  if (tid == 0)
    partials[b * 18 + blockIdx.x * 2 + blockIdx.y] =
        (red[0] + red[1]) + (red[2] + red[3]);
}

__global__ void sm_inv(const float* __restrict__ partials, float* __restrict__ invb)
{
  const int b = threadIdx.x;
  if (b < 64) {
    float s = 0.f;
    #pragma unroll
    for (int i = 0; i < 18; ++i) s += partials[b * 18 + i];
    invb[b] = 1.f / s;
  }
}

__global__ __launch_bounds__(256) void sm_norm(float* __restrict__ out,
                                               const float* __restrict__ invb)
{
  const int i4 = blockIdx.x * 256 + threadIdx.x;
  if (i4 < 1050624) {
    const int b = i4 / 16416;
    float4 v = ((float4*)out)[i4];
    const float s = invb[b];
    v.x *= s; v.y *= s; v.z *= s; v.w *= s;
    ((float4*)out)[i4] = v;
  }
}

// ---------------------------------------------------------------------------
extern "C" void kernel_launch(void* const* d_in, const int* in_sizes, int n_in,
                              void* d_out, int out_size, void* d_ws, size_t ws_size,
                              hipStream_t stream)
{
  const float* machine = (const float*)d_in[0];
  const float* jobs    = (const float*)d_in[1];
  const float* mask    = (const float*)d_in[2];
  const float* Wq      = (const float*)d_in[3];
  const float* Wk      = (const float*)d_in[4];
  const float* Wv      = (const float*)d_in[5];
  const float* Wc      = (const float*)d_in[6];
  const float* bc      = (const float*)d_in[7];
  const float* skip    = (const float*)d_in[8];

  // Workspace (floats). Peak 20,905,088 f ~ 83.6 MB.
  //   [0,        2097152)  Qw; overwritten in-place by attn_fused as OC
  //   [2097152, 10502144)  Kw; first 1216 f reused as partials/invb after attn
  //   [10502144,18907136)  Vw
  //   [18907136,...)       Wth/Wtl (bf16) -> dead after kv gemm -> MH
  float* ws       = (float*)d_ws;
  float* Qw       = ws;
  float* Kw       = ws + 2097152;
  float* Vw       = ws + 10502144;
  unsigned short* Wth = (unsigned short*)(ws + 18907136);
  unsigned short* Wtl = Wth + 131072;
  float* MH       = ws + 18907136;     // overlays Wt (dead by then)
  float* partials = ws + 2097152;      // overlays Kw (dead after attn)
  float* invb     = partials + 1152;
  float* OC       = Qw;                // attn writes its own (h,b) slice only
  float* out      = (float*)d_out;

  // Q = machine @ Wq3 (fp32)
  gemm_wide<0><<<dim3(2, 128), 256, 0, stream>>>(
      machine, nullptr, nullptr, Wq, nullptr, Qw);
  // W split/transpose, then K|V = vjobs @ [Wk|Wv] via split-bf16 MFMA
  prep_wt<<<512, 256, 0, stream>>>(Wk, Wv, Wth, Wtl);
  gemm_kv_mfma<<<dim3(4, 257), 256, 0, stream>>>(jobs, skip, Wth, Wtl, Kw, Vw);
  // fused attention: 4 T-chunk waves per (h,b), in-block reduce, writes OC
  attn_fused<<<dim3(16, 64), 256, 0, stream>>>(Qw, Kw, Vw, OC);
  // mh = out_concat @ Wc + bc (fp32)
  gemm_wide<0><<<dim3(2, 128), 256, 0, stream>>>(
      OC, nullptr, nullptr, Wc, bc, MH);
  // exp(logits-10) + partials
  logits_gemm<<<dim3(9, 2, 64), 256, 0, stream>>>(MH, jobs, skip, mask, out, partials);
  sm_inv<<<1, 64, 0, stream>>>(partials, invb);
  sm_norm<<<4104, 256, 0, stream>>>(out, invb);
}

// Round 10
// 333.262 us; speedup vs baseline: 1.4224x; 1.0135x over previous
//
#include <hip/hip_runtime.h>
#include <math.h>

// B=64, M=128, J=512, T=513, E=256, H=16, D=16; out (64, 65664) fp32.

#define LDT 68    // 64-row A-tile LDS leading dim (fp32 gemms)
#define LDB 132   // 128-col B-tile LDS leading dim (fp32 gemms)

typedef __attribute__((ext_vector_type(8))) short bf16x8;   // 8 bf16 = 4 VGPR
typedef __attribute__((ext_vector_type(4))) float f32x4;    // MFMA acc

static __device__ inline unsigned short f2bf(float x) {     // RNE fp32->bf16
  unsigned u = __float_as_uint(x);
  return (unsigned short)((u + 0x7fffu + ((u >> 16) & 1u)) >> 16);
}
static __device__ inline float bf2f(unsigned short h) {
  return __uint_as_float(((unsigned)h) << 16);
}
static __device__ inline unsigned pk(unsigned short a, unsigned short b) {
  return (unsigned)a | ((unsigned)b << 16);
}

// ---------------------------------------------------------------------------
// One-time W split+transpose: Wt[col][k] (bf16 hi/lo), col 0..255 = Wk cols,
// 256..511 = Wv cols. grid 512 blocks x 256 thr (thread = k).
// ---------------------------------------------------------------------------
__global__ void prep_wt(const float* __restrict__ Wk, const float* __restrict__ Wv,
                        unsigned short* __restrict__ Wth, unsigned short* __restrict__ Wtl)
{
  const int c = blockIdx.x, k = threadIdx.x;
  const float x = (c < 256) ? Wk[k * 256 + c] : Wv[k * 256 + (c - 256)];
  const unsigned short h = f2bf(x);
  Wth[c * 256 + k] = h;
  Wtl[c * 256 + k] = f2bf(x - bf2f(h));
}

// ---------------------------------------------------------------------------
// Split-bf16 MFMA GEMM: C(32832 x 512) = vjobs(32832 x 256) @ [Wk|Wv].
// 128x128 tile, 256 thr = 4 waves (2x2, each 64x64 via 4x4 16x16x32 tiles).
// C = Ah*Bh + Ah*Bl + Al*Bh  (error ~2^-17, fp32-grade for this use).
// ---------------------------------------------------------------------------
__global__ __launch_bounds__(256) void gemm_kv_mfma(
    const float* __restrict__ jobs, const float* __restrict__ skip,
    const unsigned short* __restrict__ Wth, const unsigned short* __restrict__ Wtl,
    float* __restrict__ Kw, float* __restrict__ Vw)
{
  __shared__ short Ah[128 * 32], Al[128 * 32];   // [row][k] bf16, 8KB each
  __shared__ short Bh[128 * 32], Bl[128 * 32];   // [col][k] bf16
  const int tid = threadIdx.x;
  const int bx = blockIdx.x, by = blockIdx.y;

  const int r16 = tid >> 1;
  const int h16 = (tid & 1) << 4;
  int rg = by * 128 + r16; if (rg > 32831) rg = 32831;
  const int bb = rg / 513, tt = rg - bb * 513;
  const float* arow = (tt == 0) ? skip : (jobs + ((size_t)(bb * 512 + tt - 1) << 8));
  const unsigned short* bhrow = Wth + ((size_t)(bx * 128 + r16) << 8);
  const unsigned short* blrow = Wtl + ((size_t)(bx * 128 + r16) << 8);

  const int w = tid >> 6, lane = tid & 63;
  const int wr = (w >> 1) << 6, wc = (w & 1) << 6;
  const int fm = lane & 15, fq = lane >> 4;

  f32x4 acc[4][4] = {};

  for (int kk = 0; kk < 256; kk += 32) {
    const float4 a0 = *(const float4*)(arow + kk + h16);
    const float4 a1 = *(const float4*)(arow + kk + h16 + 4);
    const float4 a2 = *(const float4*)(arow + kk + h16 + 8);
    const float4 a3 = *(const float4*)(arow + kk + h16 + 12);
    const int4 bh0 = *(const int4*)(bhrow + kk + h16);
    const int4 bh1 = *(const int4*)(bhrow + kk + h16 + 8);
    const int4 bl0 = *(const int4*)(blrow + kk + h16);
    const int4 bl1 = *(const int4*)(blrow + kk + h16 + 8);

    unsigned short h[16], l[16];
    const float av[16] = {a0.x,a0.y,a0.z,a0.w, a1.x,a1.y,a1.z,a1.w,
                          a2.x,a2.y,a2.z,a2.w, a3.x,a3.y,a3.z,a3.w};
    #pragma unroll
    for (int i = 0; i < 16; ++i) {
      h[i] = f2bf(av[i]);
      l[i] = f2bf(av[i] - bf2f(h[i]));
    }

    __syncthreads();
    const int so = r16 * 32 + h16;
    ((int4*)&Ah[so])[0] = make_int4(pk(h[0],h[1]), pk(h[2],h[3]), pk(h[4],h[5]), pk(h[6],h[7]));
    ((int4*)&Ah[so])[1] = make_int4(pk(h[8],h[9]), pk(h[10],h[11]), pk(h[12],h[13]), pk(h[14],h[15]));
    ((int4*)&Al[so])[0] = make_int4(pk(l[0],l[1]), pk(l[2],l[3]), pk(l[4],l[5]), pk(l[6],l[7]));
    ((int4*)&Al[so])[1] = make_int4(pk(l[8],l[9]), pk(l[10],l[11]), pk(l[12],l[13]), pk(l[14],l[15]));
    *(int4*)&Bh[so] = bh0; *(int4*)&Bh[so + 8] = bh1;
    *(int4*)&Bl[so] = bl0; *(int4*)&Bl[so + 8] = bl1;
    __syncthreads();

    bf16x8 afh[4], afl[4], bfh[4], bfl[4];
    #pragma unroll
    for (int i = 0; i < 4; ++i) {
      const int ai = (wr + i * 16 + fm) * 32 + fq * 8;
      const int bi = (wc + i * 16 + fm) * 32 + fq * 8;
      afh[i] = *(const bf16x8*)&Ah[ai];
      afl[i] = *(const bf16x8*)&Al[ai];
      bfh[i] = *(const bf16x8*)&Bh[bi];
      bfl[i] = *(const bf16x8*)&Bl[bi];
    }
    #pragma unroll
    for (int mi = 0; mi < 4; ++mi)
      #pragma unroll
      for (int ni = 0; ni < 4; ++ni) {
        acc[mi][ni] = __builtin_amdgcn_mfma_f32_16x16x32_bf16(afh[mi], bfl[ni], acc[mi][ni], 0, 0, 0);
        acc[mi][ni] = __builtin_amdgcn_mfma_f32_16x16x32_bf16(afl[mi], bfh[ni], acc[mi][ni], 0, 0, 0);
        acc[mi][ni] = __builtin_amdgcn_mfma_f32_16x16x32_bf16(afh[mi], bfh[ni], acc[mi][ni], 0, 0, 0);
      }
  }

  float* Cb = (bx < 2) ? Kw : Vw;
  const int cb = ((bx & 1) << 7) + wc;
  #pragma unroll
  for (int mi = 0; mi < 4; ++mi) {
    #pragma unroll
    for (int r = 0; r < 4; ++r) {
      const int row = by * 128 + wr + mi * 16 + fq * 4 + r;
      if (row < 32832) {
        float* crow = Cb + (size_t)row * 256 + cb;
        #pragma unroll
        for (int ni = 0; ni < 4; ++ni)
          crow[ni * 16 + fm] = acc[mi][ni][r];
      }
    }
  }
}

// ---------------------------------------------------------------------------
// Wide tiled fp32 GEMM (Q and Wc projections): C[rows x 256] = A @ W (+bias)
// ---------------------------------------------------------------------------
template<int MODE>
__global__ __launch_bounds__(256) void gemm_wide(
    const float* __restrict__ A, const float* __restrict__ jobs,
    const float* __restrict__ skip, const float* __restrict__ W1,
    const float* __restrict__ bias, float* __restrict__ C1)
{
  __shared__ float As[16 * LDT];
  __shared__ float Bs[16 * LDB];
  const int tid = threadIdx.x;
  const int bx = blockIdx.x, by = blockIdx.y;

  const float* W = W1; float* C = C1; const int col0 = bx * 128;

  const int a_row = tid >> 2;
  const int a_k4  = (tid & 3) << 2;
  const int row = by * 64 + a_row;
  const float* arow;
  if (MODE == 0) {
    arow = A + ((size_t)row << 8);
  } else {
    const int bb = row / 513;
    const int t  = row - bb * 513;
    arow = (t == 0) ? skip : (jobs + ((size_t)(bb * 512 + t - 1) << 8));
  }

  const int b_k  = tid >> 4;
  const int b_c8 = (tid & 15) << 3;

  const int tr = tid >> 4, tc = tid & 15;
  float acc[4][8] = {};

  for (int k0 = 0; k0 < 256; k0 += 16) {
    const float4 av  = *(const float4*)(arow + k0 + a_k4);
    const float4 bv0 = *(const float4*)(W + ((size_t)(k0 + b_k) << 8) + col0 + b_c8);
    const float4 bv1 = *(const float4*)(W + ((size_t)(k0 + b_k) << 8) + col0 + b_c8 + 4);
    __syncthreads();
    As[(a_k4 + 0) * LDT + a_row] = av.x;
    As[(a_k4 + 1) * LDT + a_row] = av.y;
    As[(a_k4 + 2) * LDT + a_row] = av.z;
    As[(a_k4 + 3) * LDT + a_row] = av.w;
    *(float4*)&Bs[b_k * LDB + b_c8]     = bv0;
    *(float4*)&Bs[b_k * LDB + b_c8 + 4] = bv1;
    __syncthreads();
    #pragma unroll
    for (int k = 0; k < 16; ++k) {
      const float4 a  = *(const float4*)&As[k * LDT + (tr << 2)];
      const float4 b0 = *(const float4*)&Bs[k * LDB + (tc << 3)];
      const float4 b1 = *(const float4*)&Bs[k * LDB + (tc << 3) + 4];
      const float aa[4] = {a.x, a.y, a.z, a.w};
      #pragma unroll
      for (int i = 0; i < 4; ++i) {
        acc[i][0] = fmaf(aa[i], b0.x, acc[i][0]);
        acc[i][1] = fmaf(aa[i], b0.y, acc[i][1]);
        acc[i][2] = fmaf(aa[i], b0.z, acc[i][2]);
        acc[i][3] = fmaf(aa[i], b0.w, acc[i][3]);
        acc[i][4] = fmaf(aa[i], b1.x, acc[i][4]);
        acc[i][5] = fmaf(aa[i], b1.y, acc[i][5]);
        acc[i][6] = fmaf(aa[i], b1.z, acc[i][6]);
        acc[i][7] = fmaf(aa[i], b1.w, acc[i][7]);
      }
    }
  }

  const int oc = col0 + (tc << 3);
  float4 bsa = make_float4(0.f,0.f,0.f,0.f), bsb = make_float4(0.f,0.f,0.f,0.f);
  if (bias) { bsa = *(const float4*)(bias + oc); bsb = *(const float4*)(bias + oc + 4); }
  #pragma unroll
  for (int i = 0; i < 4; ++i) {
    float* crow = C + ((size_t)(by * 64 + (tr << 2) + i) << 8) + oc;
    float4 o0, o1;
    o0.x = acc[i][0]+bsa.x; o0.y = acc[i][1]+bsa.y; o0.z = acc[i][2]+bsa.z; o0.w = acc[i][3]+bsa.w;
    o1.x = acc[i][4]+bsb.x; o1.y = acc[i][5]+bsb.y; o1.z = acc[i][6]+bsb.z; o1.w = acc[i][7]+bsb.w;
    *(float4*)crow = o0; *(float4*)(crow + 4) = o1;
  }
}

// ---------------------------------------------------------------------------
// Attention v6 (fused): one block per (h, b), 256 thr = 4 waves; wave w owns
// T-chunk [w*128, min(w*128+128, 513)); each lane owns m=lane and m=lane+64.
// launch_bounds(256,4) -> 128-VGPR cap fits the working set (no spill).
// readfirstlane keeps K/V s_loads scalar; 4 waves/SIMD hide lgkmcnt waits.
// 2-stage LDS tree reduce, writes final normalized OC.
// ---------------------------------------------------------------------------
__global__ __launch_bounds__(256, 4) void attn_fused(
    const float* __restrict__ Q, const float* __restrict__ K,
    const float* __restrict__ V, float* __restrict__ OC)
{
  const int h = blockIdx.x, b = blockIdx.y;
  const int tid = threadIdx.x;
  const int lane = tid & 63;
  const int w = __builtin_amdgcn_readfirstlane(tid >> 6);  // 0..3, SGPR
  const int ts = w << 7;
  const int te = (w == 3) ? 513 : (ts + 128);

  __shared__ float red[2 * 128 * 17];    // 17 KB, 2 reduction slots

  float q0[16], q1[16];
  {
    const float* qp0 = Q + ((size_t)(b * 128 + lane) << 8) + h * 16;
    const float* qp1 = qp0 + (64 << 8);
    #pragma unroll
    for (int i = 0; i < 16; i += 4) {
      const float4 a = *(const float4*)(qp0 + i);
      const float4 d = *(const float4*)(qp1 + i);
      q0[i] = a.x * 0.25f; q0[i+1] = a.y * 0.25f; q0[i+2] = a.z * 0.25f; q0[i+3] = a.w * 0.25f;
      q1[i] = d.x * 0.25f; q1[i+1] = d.y * 0.25f; q1[i+2] = d.z * 0.25f; q1[i+3] = d.w * 0.25f;
    }
  }

  float l0 = 0.f, l1 = 0.f, o0[16] = {}, o1[16] = {};
  const float* kp = K + ((size_t)(b * 513 + ts) << 8) + h * 16;
  const float* vp = V + ((size_t)(b * 513 + ts) << 8) + h * 16;

#define DOT16(Q_, P_, S_) do { \
    float s0_ = Q_[0]*(P_)[0];  s0_ = fmaf(Q_[1],(P_)[1],s0_);  s0_ = fmaf(Q_[2],(P_)[2],s0_);  s0_ = fmaf(Q_[3],(P_)[3],s0_); \
    float s1_ = Q_[4]*(P_)[4];  s1_ = fmaf(Q_[5],(P_)[5],s1_);  s1_ = fmaf(Q_[6],(P_)[6],s1_);  s1_ = fmaf(Q_[7],(P_)[7],s1_); \
    float s2_ = Q_[8]*(P_)[8];  s2_ = fmaf(Q_[9],(P_)[9],s2_);  s2_ = fmaf(Q_[10],(P_)[10],s2_); s2_ = fmaf(Q_[11],(P_)[11],s2_); \
    float s3_ = Q_[12]*(P_)[12]; s3_ = fmaf(Q_[13],(P_)[13],s3_); s3_ = fmaf(Q_[14],(P_)[14],s3_); s3_ = fmaf(Q_[15],(P_)[15],s3_); \
    S_ = (s0_ + s1_) + (s2_ + s3_); } while (0)

#define ACC16(O_, E_, P_) do { \
    O_[0]=fmaf(E_,(P_)[0],O_[0]);   O_[1]=fmaf(E_,(P_)[1],O_[1]); \
    O_[2]=fmaf(E_,(P_)[2],O_[2]);   O_[3]=fmaf(E_,(P_)[3],O_[3]); \
    O_[4]=fmaf(E_,(P_)[4],O_[4]);   O_[5]=fmaf(E_,(P_)[5],O_[5]); \
    O_[6]=fmaf(E_,(P_)[6],O_[6]);   O_[7]=fmaf(E_,(P_)[7],O_[7]); \
    O_[8]=fmaf(E_,(P_)[8],O_[8]);   O_[9]=fmaf(E_,(P_)[9],O_[9]); \
    O_[10]=fmaf(E_,(P_)[10],O_[10]); O_[11]=fmaf(E_,(P_)[11],O_[11]); \
    O_[12]=fmaf(E_,(P_)[12],O_[12]); O_[13]=fmaf(E_,(P_)[13],O_[13]); \
    O_[14]=fmaf(E_,(P_)[14],O_[14]); O_[15]=fmaf(E_,(P_)[15],O_[15]); } while (0)

  int t = ts;
  for (; t + 1 < te; t += 2) {
    float ea0, eb0, ea1, eb1;
    {
      const float* ka = kp;          // rows t, t+1 (uniform -> SGPRs)
      const float* kb = kp + 256;
      DOT16(q0, ka, ea0); DOT16(q0, kb, eb0);
      DOT16(q1, ka, ea1); DOT16(q1, kb, eb1);
    }
    ea0 = __expf(ea0); eb0 = __expf(eb0);
    ea1 = __expf(ea1); eb1 = __expf(eb1);
    l0 += ea0 + eb0; l1 += ea1 + eb1;
    {
      const float* va = vp;
      const float* vb = vp + 256;
      ACC16(o0, ea0, va); ACC16(o0, eb0, vb);
      ACC16(o1, ea1, va); ACC16(o1, eb1, vb);
    }
    kp += 512; vp += 512;
  }
  if (t < te) {   // odd tail (wave 3 only: 129 rows)
    float s0, s1;
    DOT16(q0, kp, s0); DOT16(q1, kp, s1);
    const float e0 = __expf(s0), e1 = __expf(s1);
    l0 += e0; l1 += e1;
    ACC16(o0, e0, vp); ACC16(o1, e1, vp);
  }
#undef DOT16
#undef ACC16

  // ---- 2-stage LDS tree reduction across the 4 waves ----
  const int base0 = lane * 17, base1 = (lane + 64) * 17;
  if (w >= 2) {                       // waves 2,3 -> slots 0,1
    float* s = red + (w - 2) * 2176;
    #pragma unroll
    for (int i = 0; i < 16; ++i) { s[base0 + i] = o0[i]; s[base1 + i] = o1[i]; }
    s[base0 + 16] = l0; s[base1 + 16] = l1;
  }
  __syncthreads();
  if (w < 2) {
    const float* s = red + w * 2176;
    #pragma unroll
    for (int i = 0; i < 16; ++i) { o0[i] += s[base0 + i]; o1[i] += s[base1 + i]; }
    l0 += s[base0 + 16]; l1 += s[base1 + 16];
  }
  __syncthreads();
  if (w == 1) {                       // wave 1 -> slot 0
    float* s = red;
    #pragma unroll
    for (int i = 0; i < 16; ++i) { s[base0 + i] = o0[i]; s[base1 + i] = o1[i]; }
    s[base0 + 16] = l0; s[base1 + 16] = l1;
  }
  __syncthreads();
  if (w == 0) {
    const float* s = red;
    #pragma unroll
    for (int i = 0; i < 16; ++i) { o0[i] += s[base0 + i]; o1[i] += s[base1 + i]; }
    l0 += s[base0 + 16]; l1 += s[base1 + 16];
    const float inv0 = 1.f / l0, inv1 = 1.f / l1;
    float* op0 = OC + ((size_t)(b * 128 + lane) << 8) + h * 16;
    float* op1 = op0 + (64 << 8);
    #pragma unroll
    for (int i = 0; i < 16; i += 4) {
      float4 v0; v0.x = o0[i]*inv0; v0.y = o0[i+1]*inv0; v0.z = o0[i+2]*inv0; v0.w = o0[i+3]*inv0;
      float4 v1; v1.x = o1[i]*inv1; v1.y = o1[i+1]*inv1; v1.z = o1[i+2]*inv1; v1.w = o1[i+3]*inv1;
      *(float4*)(op0 + i) = v0;
      *(float4*)(op1 + i) = v1;
    }
  }
}

// ---------------------------------------------------------------------------
// Logits via split-bf16 MFMA (same validated skeleton as gemm_kv_mfma):
// C(128 x 513) per b = MH(128 x 256) @ vjobs(b)^T. A = MH rows, B = vjobs
// rows (row-major [t][k] IS the B [col][k] layout). Both split inline.
// Fused epilogue: e = exp(10*tanh(x/16)+mask-10), write out, deterministic
// per-block partial -> partials[b*5 + bx]. grid (5 t-tiles, 64 b).
// bx=4 covers only t=512 (write-guarded).
// ---------------------------------------------------------------------------
__global__ __launch_bounds__(256) void logits_mfma(
    const float* __restrict__ MH, const float* __restrict__ jobs,
    const float* __restrict__ skip, const float* __restrict__ mask,
    float* __restrict__ out, float* __restrict__ partials)
{
  __shared__ short Ah[128 * 32], Al[128 * 32];   // MH  [m][k] bf16 hi/lo
  __shared__ short Bh[128 * 32], Bl[128 * 32];   // jobs[t][k] bf16 hi/lo
  __shared__ float red[4];
  const int tid = threadIdx.x;
  const int bx = blockIdx.x;       // t-tile 0..4
  const int b  = blockIdx.y;

  const int r16 = tid >> 1;
  const int h16 = (tid & 1) << 4;
  const float* arow = MH + ((size_t)(b * 128 + r16) << 8);
  int tg = bx * 128 + r16; if (tg > 512) tg = 512;
  const float* brow = (tg == 0) ? skip : (jobs + ((size_t)(b * 512 + tg - 1) << 8));

  const int w = tid >> 6, lane = tid & 63;
  const int wr = (w >> 1) << 6, wc = (w & 1) << 6;
  const int fm = lane & 15, fq = lane >> 4;

  f32x4 acc[4][4] = {};

  for (int kk = 0; kk < 256; kk += 32) {
    const float4 a0 = *(const float4*)(arow + kk + h16);
    const float4 a1 = *(const float4*)(arow + kk + h16 + 4);
    const float4 a2 = *(const float4*)(arow + kk + h16 + 8);
    const float4 a3 = *(const float4*)(arow + kk + h16 + 12);
    const float4 b0 = *(const float4*)(brow + kk + h16);
    const float4 b1 = *(const float4*)(brow + kk + h16 + 4);
    const float4 b2 = *(const float4*)(brow + kk + h16 + 8);
    const float4 b3 = *(const float4*)(brow + kk + h16 + 12);

    unsigned short ha[16], la[16], hb[16], lb[16];
    const float av[16] = {a0.x,a0.y,a0.z,a0.w, a1.x,a1.y,a1.z,a1.w,
                          a2.x,a2.y,a2.z,a2.w, a3.x,a3.y,a3.z,a3.w};
    const float bv[16] = {b0.x,b0.y,b0.z,b0.w, b1.x,b1.y,b1.z,b1.w,
                          b2.x,b2.y,b2.z,b2.w, b3.x,b3.y,b3.z,b3.w};
    #pragma unroll
    for (int i = 0; i < 16; ++i) {
      ha[i] = f2bf(av[i]); la[i] = f2bf(av[i] - bf2f(ha[i]));
      hb[i] = f2bf(bv[i]); lb[i] = f2bf(bv[i] - bf2f(hb[i]));
    }

    __syncthreads();
    const int so = r16 * 32 + h16;
    ((int4*)&Ah[so])[0] = make_int4(pk(ha[0],ha[1]), pk(ha[2],ha[3]), pk(ha[4],ha[5]), pk(ha[6],ha[7]));
    ((int4*)&Ah[so])[1] = make_int4(pk(ha[8],ha[9]), pk(ha[10],ha[11]), pk(ha[12],ha[13]), pk(ha[14],ha[15]));
    ((int4*)&Al[so])[0] = make_int4(pk(la[0],la[1]), pk(la[2],la[3]), pk(la[4],la[5]), pk(la[6],la[7]));
    ((int4*)&Al[so])[1] = make_int4(pk(la[8],la[9]), pk(la[10],la[11]), pk(la[12],la[13]), pk(la[14],la[15]));
    ((int4*)&Bh[so])[0] = make_int4(pk(hb[0],hb[1]), pk(hb[2],hb[3]), pk(hb[4],hb[5]), pk(hb[6],hb[7]));
    ((int4*)&Bh[so])[1] = make_int4(pk(hb[8],hb[9]), pk(hb[10],hb[11]), pk(hb[12],hb[13]), pk(hb[14],hb[15]));
    ((int4*)&Bl[so])[0] = make_int4(pk(lb[0],lb[1]), pk(lb[2],lb[3]), pk(lb[4],lb[5]), pk(lb[6],lb[7]));
    ((int4*)&Bl[so])[1] = make_int4(pk(lb[8],lb[9]), pk(lb[10],lb[11]), pk(lb[12],lb[13]), pk(lb[14],lb[15]));
    __syncthreads();

    bf16x8 afh[4], afl[4], bfh[4], bfl[4];
    #pragma unroll
    for (int i = 0; i < 4; ++i) {
      const int ai = (wr + i * 16 + fm) * 32 + fq * 8;
      const int bi = (wc + i * 16 + fm) * 32 + fq * 8;
      afh[i] = *(const bf16x8*)&Ah[ai];
      afl[i] = *(const bf16x8*)&Al[ai];
      bfh[i] = *(const bf16x8*)&Bh[bi];
      bfl[i] = *(const bf16x8*)&Bl[bi];
    }
    #pragma unroll
    for (int mi = 0; mi < 4; ++mi)
      #pragma unroll
      for (int ni = 0; ni < 4; ++ni) {
        acc[mi][ni] = __builtin_amdgcn_mfma_f32_16x16x32_bf16(afh[mi], bfl[ni], acc[mi][ni], 0, 0, 0);
        acc[mi][ni] = __builtin_amdgcn_mfma_f32_16x16x32_bf16(afl[mi], bfh[ni], acc[mi][ni], 0, 0, 0);
        acc[mi][ni] = __builtin_amdgcn_mfma_f32_16x16x32_bf16(afh[mi], bfh[ni], acc[mi][ni], 0, 0, 0);
      }
  }

  // epilogue: lg = 10*tanh(acc/16) + mask; e = exp(lg-10); sum
  float lsum = 0.f;
  #pragma unroll
  for (int mi = 0; mi < 4; ++mi) {
    #pragma unroll
    for (int r = 0; r < 4; ++r) {
      const int m = wr + mi * 16 + fq * 4 + r;
      #pragma unroll
      for (int ni = 0; ni < 4; ++ni) {
        const int t = bx * 128 + wc + ni * 16 + fm;
        if (t < 513) {
          const float lg = 10.f * tanhf(acc[mi][ni][r] * 0.0625f)
                         + mask[((size_t)(b * 128 + m)) * 513 + t];
          const float e = __expf(lg - 10.f);
          out[(size_t)b * 65664 + (size_t)m * 513 + t] = e;
          lsum += e;
        }
      }
    }
  }
  #pragma unroll
  for (int off = 32; off; off >>= 1) lsum += __shfl_xor(lsum, off);
  if (lane == 0) red[w] = lsum;
  __syncthreads();
  if (tid == 0)
    partials[b * 5 + bx] = (red[0] + red[1]) + (red[2] + red[3]);
}

// Reduce 5 partials per batch -> 1/sum.
__global__ void sm_inv(const float* __restrict__ partials, float* __restrict__ invb)
{
  const int b = threadIdx.x;
  if (b < 64) {
    float s = 0.f;
    #pragma unroll
    for (int i = 0; i < 5; ++i) s += partials[b * 5 + i];
    invb[b] = 1.f / s;
  }
}

__global__ __launch_bounds__(256) void sm_norm(float* __restrict__ out,
                                               const float* __restrict__ invb)
{
  const int i4 = blockIdx.x * 256 + threadIdx.x;
  if (i4 < 1050624) {
    const int b = i4 / 16416;
    float4 v = ((float4*)out)[i4];
    const float s = invb[b];
    v.x *= s; v.y *= s; v.z *= s; v.w *= s;
    ((float4*)out)[i4] = v;
  }
}

// ---------------------------------------------------------------------------
extern "C" void kernel_launch(void* const* d_in, const int* in_sizes, int n_in,
                              void* d_out, int out_size, void* d_ws, size_t ws_size,
                              hipStream_t stream)
{
  const float* machine = (const float*)d_in[0];
  const float* jobs    = (const float*)d_in[1];
  const float* mask    = (const float*)d_in[2];
  const float* Wq      = (const float*)d_in[3];
  const float* Wk      = (const float*)d_in[4];
  const float* Wv      = (const float*)d_in[5];
  const float* Wc      = (const float*)d_in[6];
  const float* bc      = (const float*)d_in[7];
  const float* skip    = (const float*)d_in[8];

  // Workspace (floats). Peak 20,905,088 f ~ 83.6 MB.
  //   [0,        2097152)  Qw; overwritten in-place by attn_fused as OC
  //   [2097152, 10502144)  Kw; first ~400 f reused as partials/invb after attn
  //   [10502144,18907136)  Vw
  //   [18907136,...)       Wth/Wtl (bf16) -> dead after kv gemm -> MH
  float* ws       = (float*)d_ws;
  float* Qw       = ws;
  float* Kw       = ws + 2097152;
  float* Vw       = ws + 10502144;
  unsigned short* Wth = (unsigned short*)(ws + 18907136);
  unsigned short* Wtl = Wth + 131072;
  float* MH       = ws + 18907136;     // overlays Wt (dead by then)
  float* partials = ws + 2097152;      // overlays Kw (dead after attn)
  float* invb     = partials + 320;
  float* OC       = Qw;                // attn writes its own (h,b) slice only
  float* out      = (float*)d_out;

  // Q = machine @ Wq3 (fp32)
  gemm_wide<0><<<dim3(2, 128), 256, 0, stream>>>(
      machine, nullptr, nullptr, Wq, nullptr, Qw);
  // W split/transpose, then K|V = vjobs @ [Wk|Wv] via split-bf16 MFMA
  prep_wt<<<512, 256, 0, stream>>>(Wk, Wv, Wth, Wtl);
  gemm_kv_mfma<<<dim3(4, 257), 256, 0, stream>>>(jobs, skip, Wth, Wtl, Kw, Vw);
  // fused attention: 4 T-chunk waves per (h,b), in-block reduce, writes OC
  attn_fused<<<dim3(16, 64), 256, 0, stream>>>(Qw, Kw, Vw, OC);
  // mh = out_concat @ Wc + bc (fp32)
  gemm_wide<0><<<dim3(2, 128), 256, 0, stream>>>(
      OC, nullptr, nullptr, Wc, bc, MH);
  // logits via split-bf16 MFMA + fused exp epilogue + partials
  logits_mfma<<<dim3(5, 64), 256, 0, stream>>>(MH, jobs, skip, mask, out, partials);
  sm_inv<<<1, 64, 0, stream>>>(partials, invb);
  sm_norm<<<4104, 256, 0, stream>>>(out, invb);
}